// Round 5
// baseline (384.741 us; speedup 1.0000x reference)
//
#include <hip/hip_runtime.h>
#include <hip/hip_bf16.h>
#include <math.h>

#define BB   16
#define SS   2048
#define HH   768
#define MAXN 400
#define LBL  97
#define MIDD 768
#define KTOT 1536   // 2*HH

#define K1_NTILE   6                      // 768/128
#define K1_RTILE   13                     // ceil(400/32)
#define K1_TILES   (K1_NTILE * K1_RTILE * BB)   // 1248
#define K2_XTILES  25                     // ceil(400/16)

// ---------------------------------------------------------------------------
// K0: zero the work-steal counter (ws is poisoned 0xAA before every call).
// ---------------------------------------------------------------------------
__global__ void k0_init(int* __restrict__ ctr) { *ctr = 0; }

// ---------------------------------------------------------------------------
// K1: fused gather + GEMM1 + bias + relu, persistent work-stealing version.
// h[b,i,:] = relu(concat(outs[b,pos1,:], outs[b,pos2,:]) @ W1 + b1)
// tile: BM=32 x BN=128 x BK=32, 256 thr, micro 4x4.
// 1024 persistent blocks steal tiles from an atomic queue -> CUs stay at
// 4 blocks (16 waves) each until the queue drains: latency hidden, balanced.
// ---------------------------------------------------------------------------
__global__ __launch_bounds__(256, 4)
void k1_gemm1(const float* __restrict__ outs, const int* __restrict__ rels_pos,
              const float* __restrict__ W1, const float* __restrict__ b1,
              float* __restrict__ h, int* __restrict__ ctr)
{
    __shared__ __align__(16) float As[32][36];   // [k][m] transposed, padded
    __shared__ __align__(16) float Bs[32][128];  // [k][n]
    __shared__ int s_tile;

    const int tid = threadIdx.x;

    // staging maps (tile-independent parts)
    const int m_st = tid >> 3;                   // 0..31
    const int kq   = (tid & 7) << 2;             // 0,4,...,28
    const int kb   = tid >> 4;                   // 0..15
    const int ng   = tid & 15;                   // 0..15
    // micro-tile map
    const int cg = tid & 31;                     // 0..31
    const int rg = tid >> 5;                     // 0..7

    for (;;) {
        if (tid == 0) s_tile = atomicAdd(ctr, 1);
        __syncthreads();
        const int t = s_tile;
        __syncthreads();                         // s_tile safe to rewrite; LDS safe to restage
        if (t >= K1_TILES) break;

        const int nt = t % K1_NTILE;             // n-tiles consecutive: A-row L2/L3 reuse
        const int rt = (t / K1_NTILE) % K1_RTILE;
        const int b  = t / (K1_NTILE * K1_RTILE);
        const int num = rels_pos[2 * b + 1];
        const int i0  = rt * 32;
        if (i0 >= num) continue;                 // inactive tile (barrier above protects)
        const int n0    = nt * 128;
        const int start = rels_pos[2 * b + 0];

        const int irow = i0 + m_st;
        int p1 = start + 4 * irow;     p1 = min(max(p1, 0), SS - 1);
        int p2 = start + 4 * irow + 2; p2 = min(max(p2, 0), SS - 1);
        const float* arow1 = outs + (size_t)(b * SS + p1) * HH;
        const float* arow2 = outs + (size_t)(b * SS + p2) * HH;

        float acc[4][4];
        #pragma unroll
        for (int r = 0; r < 4; ++r)
            #pragma unroll
            for (int c = 0; c < 4; ++c) acc[r][c] = 0.f;

        // register prefetch of first k-tile
        float4 aReg, bR00, bR01, bR10, bR11;
        {
            aReg = *(const float4*)(arow1 + kq);
            const float* w0 = W1 + (size_t)kb * MIDD + n0;
            const float* w1 = W1 + (size_t)(kb + 16) * MIDD + n0;
            bR00 = *(const float4*)(w0 + ng * 4);
            bR01 = *(const float4*)(w0 + ng * 4 + 64);
            bR10 = *(const float4*)(w1 + ng * 4);
            bR11 = *(const float4*)(w1 + ng * 4 + 64);
        }

        for (int kt = 0; kt < KTOT / 32; ++kt) {
            As[kq + 0][m_st] = aReg.x;
            As[kq + 1][m_st] = aReg.y;
            As[kq + 2][m_st] = aReg.z;
            As[kq + 3][m_st] = aReg.w;
            *(float4*)&Bs[kb][ng * 4]           = bR00;
            *(float4*)&Bs[kb][ng * 4 + 64]      = bR01;
            *(float4*)&Bs[kb + 16][ng * 4]      = bR10;
            *(float4*)&Bs[kb + 16][ng * 4 + 64] = bR11;
            __syncthreads();

            if (kt + 1 < KTOT / 32) {            // overlap next tile's global loads
                const int k0 = (kt + 1) * 32;
                const float* s = (k0 < HH) ? (arow1 + k0) : (arow2 + (k0 - HH));
                aReg = *(const float4*)(s + kq);
                const float* w0 = W1 + (size_t)(k0 + kb) * MIDD + n0;
                const float* w1 = W1 + (size_t)(k0 + kb + 16) * MIDD + n0;
                bR00 = *(const float4*)(w0 + ng * 4);
                bR01 = *(const float4*)(w0 + ng * 4 + 64);
                bR10 = *(const float4*)(w1 + ng * 4);
                bR11 = *(const float4*)(w1 + ng * 4 + 64);
            }

            // 2-deep software pipeline: fragments of k+1 in flight during k's FMAs
            float4 aC = *(const float4*)&As[0][rg * 4];
            float4 bC = *(const float4*)&Bs[0][cg * 4];
            #pragma unroll
            for (int k = 0; k < 32; ++k) {
                float4 aN, bN;
                if (k < 31) {
                    aN = *(const float4*)&As[k + 1][rg * 4];
                    bN = *(const float4*)&Bs[k + 1][cg * 4];
                }
                const float ar[4] = {aC.x, aC.y, aC.z, aC.w};
                #pragma unroll
                for (int r = 0; r < 4; ++r) {
                    acc[r][0] += ar[r] * bC.x;
                    acc[r][1] += ar[r] * bC.y;
                    acc[r][2] += ar[r] * bC.z;
                    acc[r][3] += ar[r] * bC.w;
                }
                if (k < 31) { aC = aN; bC = bN; }
            }
            __syncthreads();
        }

        // epilogue: bias + relu + store (registers + global only; no LDS)
        const float4 b1v = *(const float4*)(b1 + n0 + cg * 4);
        #pragma unroll
        for (int r = 0; r < 4; ++r) {
            const int i = i0 + rg * 4 + r;
            if (i < MAXN) {
                float4 o;
                o.x = fmaxf(acc[r][0] + b1v.x, 0.f);
                o.y = fmaxf(acc[r][1] + b1v.y, 0.f);
                o.z = fmaxf(acc[r][2] + b1v.z, 0.f);
                o.w = fmaxf(acc[r][3] + b1v.w, 0.f);
                *(float4*)&h[((size_t)b * MAXN + i) * MIDD + n0 + cg * 4] = o;
            }
        }
    }
}

// ---------------------------------------------------------------------------
// K2: fused GEMM2 + bias + log-softmax + NLL + argmax, rewritten.
// Block = 16 rows, 4 waves x 4 rows. Lane l owns cols l and l+64.
// h tile staged ONCE to LDS transposed [k][row] (49 KB, single barrier).
// W2 never touches LDS: coalesced row reads from L2, 8-k register dbuf.
// ---------------------------------------------------------------------------
__global__ __launch_bounds__(256, 2)
void k2_head(const float* __restrict__ h, const int* __restrict__ rels,
             const int* __restrict__ rels_pos,
             const float* __restrict__ W2, const float* __restrict__ b2,
             float* __restrict__ out, float* __restrict__ partials)
{
    const int b   = blockIdx.y;
    const int i0  = blockIdx.x * 16;
    const int num = rels_pos[2 * b + 1];
    const int tid = threadIdx.x;
    const int blk = blockIdx.y * gridDim.x + blockIdx.x;

    if (tid < 16) {                              // masked rows: pred = label = -1
        const int i = i0 + tid;
        if (i < MAXN && i >= num) {
            out[1 + b * MAXN + i] = -1.0f;
            out[1 + BB * MAXN + b * MAXN + i] = -1.0f;
        }
    }
    if (i0 >= num) { if (tid == 0) partials[blk] = 0.f; return; }

    __shared__ __align__(16) float hs[MIDD][16]; // [k][row], 49 KB
    __shared__ float wave_nll[4];

    // stage h tile transposed (once). row = tid&15 -> ~4-way banks on writes (cheap).
    {
        const int row = tid & 15;
        const int kc0 = (tid >> 4) * 4;          // 0..60 step 4
        const int hrow_i = min(i0 + row, MAXN - 1);
        const float* hrow = h + ((size_t)b * MAXN + hrow_i) * MIDD;
        #pragma unroll
        for (int j = 0; j < 12; ++j) {
            const int k = kc0 + j * 64;
            const float4 v = *(const float4*)(hrow + k);
            hs[k + 0][row] = v.x;
            hs[k + 1][row] = v.y;
            hs[k + 2][row] = v.z;
            hs[k + 3][row] = v.w;
        }
    }
    __syncthreads();

    const int lane = tid & 63;
    const int wv   = tid >> 6;
    const int c    = lane;
    const bool has2 = (lane + 64) < LBL;
    const int c2   = has2 ? (lane + 64) : (LBL - 1);

    float acc0[4], acc1[4];
    #pragma unroll
    for (int r = 0; r < 4; ++r) { acc0[r] = 0.f; acc1[r] = 0.f; }

    // W2 register double-buffer, 8-k batches (coalesced 64-lane row reads, L2-hit)
    float wA[8], wB[8], nAr[8], nBr[8];
    #pragma unroll
    for (int j = 0; j < 8; ++j) {
        wA[j] = W2[(size_t)j * LBL + c];
        wB[j] = W2[(size_t)j * LBL + c2];
    }
    for (int kbase = 0; kbase < MIDD; kbase += 8) {
        const bool more = (kbase + 8) < MIDD;
        if (more) {
            #pragma unroll
            for (int j = 0; j < 8; ++j) {
                nAr[j] = W2[(size_t)(kbase + 8 + j) * LBL + c];
                nBr[j] = W2[(size_t)(kbase + 8 + j) * LBL + c2];
            }
        }
        #pragma unroll
        for (int j = 0; j < 8; ++j) {
            const float4 hv = *(const float4*)&hs[kbase + j][wv * 4];  // broadcast b128
            acc0[0] += hv.x * wA[j]; acc0[1] += hv.y * wA[j];
            acc0[2] += hv.z * wA[j]; acc0[3] += hv.w * wA[j];
            acc1[0] += hv.x * wB[j]; acc1[1] += hv.y * wB[j];
            acc1[2] += hv.z * wB[j]; acc1[3] += hv.w * wB[j];
        }
        if (more) {
            #pragma unroll
            for (int j = 0; j < 8; ++j) { wA[j] = nAr[j]; wB[j] = nBr[j]; }
        }
    }
    const float bc  = b2[c];
    const float bc2 = b2[c2];
    #pragma unroll
    for (int r = 0; r < 4; ++r) { acc0[r] += bc; acc1[r] += bc2; }

    // per-row softmax / nll / argmax via wave reductions
    float nll_acc = 0.f;
    #pragma unroll
    for (int r = 0; r < 4; ++r) {
        const int i = i0 + wv * 4 + r;
        if (i >= num || i >= MAXN) continue;
        const float v1 = acc0[r];
        const float v2 = has2 ? acc1[r] : -INFINITY;
        float bv = v1; int bi = c;
        if (v2 > v1) { bv = v2; bi = lane + 64; }
        #pragma unroll
        for (int off = 32; off > 0; off >>= 1) {
            const float ov = __shfl_xor(bv, off);
            const int   oi = __shfl_xor(bi, off);
            if (ov > bv || (ov == bv && oi < bi)) { bv = ov; bi = oi; }  // first-max
        }
        float se = expf(v1 - bv) + (has2 ? expf(v2 - bv) : 0.f);
        #pragma unroll
        for (int off = 32; off > 0; off >>= 1) se += __shfl_xor(se, off);
        const int lbl = rels[b * MAXN + i];
        float tv = (c == lbl ? v1 : 0.f) + ((has2 && (lane + 64) == lbl) ? v2 : 0.f);
        #pragma unroll
        for (int off = 32; off > 0; off >>= 1) tv += __shfl_xor(tv, off);
        const float nll = bv + logf(se) - tv;     // m + lse - logit[label]
        if (lane == 0) {
            nll_acc += nll;
            out[1 + b * MAXN + i] = (float)bi;
            out[1 + BB * MAXN + b * MAXN + i] = (float)lbl;
        }
    }
    if (lane == 0) wave_nll[wv] = nll_acc;
    __syncthreads();
    if (tid == 0)
        partials[blk] = wave_nll[0] + wave_nll[1] + wave_nll[2] + wave_nll[3];
}

// ---------------------------------------------------------------------------
// K3: reduce partial NLL sums, divide by mask count, write loss.
// ---------------------------------------------------------------------------
__global__ void k3_final(const float* __restrict__ partials,
                         const int* __restrict__ rels_pos, float* __restrict__ out)
{
    const int lane = threadIdx.x;   // 64 threads
    float v = 0.f;
    for (int idx = lane; idx < K2_XTILES * BB; idx += 64) v += partials[idx];
    #pragma unroll
    for (int off = 32; off > 0; off >>= 1) v += __shfl_xor(v, off);
    float cnt = (lane < BB) ? (float)min(max(rels_pos[2 * lane + 1], 0), MAXN) : 0.f;
    #pragma unroll
    for (int off = 32; off > 0; off >>= 1) cnt += __shfl_xor(cnt, off);
    if (lane == 0) out[0] = v / cnt;
}

extern "C" void kernel_launch(void* const* d_in, const int* in_sizes, int n_in,
                              void* d_out, int out_size, void* d_ws, size_t ws_size,
                              hipStream_t stream)
{
    const float* outs     = (const float*)d_in[0];
    const int*   rels     = (const int*)  d_in[1];
    const int*   rels_pos = (const int*)  d_in[2];
    const float* W1       = (const float*)d_in[3];
    const float* b1       = (const float*)d_in[4];
    const float* W2       = (const float*)d_in[5];
    const float* b2       = (const float*)d_in[6];
    float* out = (float*)d_out;

    float* h        = (float*)d_ws;                        // 6400 x 768 f32
    float* partials = h + (size_t)BB * MAXN * MIDD;        // 400 floats
    int*   ctr      = (int*)(partials + K2_XTILES * BB);   // steal counter

    hipLaunchKernelGGL(k0_init, dim3(1), dim3(1), 0, stream, ctr);

    hipLaunchKernelGGL(k1_gemm1, dim3(1024), dim3(256), 0, stream,
                       outs, rels_pos, W1, b1, h, ctr);

    dim3 g2(K2_XTILES, BB);                                // (25, 16)
    hipLaunchKernelGGL(k2_head, g2, dim3(256), 0, stream,
                       h, rels, rels_pos, W2, b2, out, partials);

    hipLaunchKernelGGL(k3_final, dim3(1), dim3(64), 0, stream, partials, rels_pos, out);
}

// Round 6
// 298.448 us; speedup vs baseline: 1.2891x; 1.2891x over previous
//
#include <hip/hip_runtime.h>
#include <hip/hip_bf16.h>
#include <math.h>

#define BB   16
#define SS   2048
#define HH   768
#define MAXN 400
#define LBL  97
#define MIDD 768
#define KTOT 1536   // 2*HH

#define K2_XTILES 25                      // ceil(400/16)
#define W1S_JOBS  (192 * 768)             // [k/8][col] b128 units per plane

typedef __attribute__((ext_vector_type(8)))  __bf16 bf16x8;
typedef __attribute__((ext_vector_type(16))) float  f32x16;

// ---------------------------------------------------------------------------
// K0: split W1 (f32 [1536][768]) into hi/lo bf16 planes, layout [k>>3][col][8]
// so K1 can load B-fragments as coalesced b128 and store b128 to LDS.
// x = hi + lo exactly at bf16x2 precision (RNE both).
// ---------------------------------------------------------------------------
__global__ __launch_bounds__(256)
void k0_split(const float* __restrict__ W1, ushort* __restrict__ hi,
              ushort* __restrict__ lo)
{
    const int job = blockIdx.x * 256 + threadIdx.x;   // 0..147455
    if (job >= W1S_JOBS) return;
    const int g   = job / 768;                        // k-octet 0..191
    const int col = job - g * 768;
    bf16x8 hv, lv;
    #pragma unroll
    for (int j = 0; j < 8; ++j) {
        const float f = W1[(size_t)(g * 8 + j) * MIDD + col];
        const __bf16 hb = (__bf16)f;                  // RNE
        hv[j] = hb;
        lv[j] = (__bf16)(f - (float)hb);
    }
    ((bf16x8*)hi)[job] = hv;
    ((bf16x8*)lo)[job] = lv;
}

// ---------------------------------------------------------------------------
// K1: fused gather + GEMM1 + bias + relu via bf16 3-pass split MFMA.
// h[b,i,:] = relu(concat(outs[b,pos1,:], outs[b,pos2,:]) @ W1 + b1)
// tile BM=64 x BN=128 x BK=32; 4 waves (2r x 2c), each 32x64 out via
// 2x v_mfma_f32_32x32x16_bf16 tiles x 3 passes (hh + hl + lh).
// LDS: A/B fragment-layout [kgrp][row|col][8] bf16, hi+lo planes (24 KB).
// A-frag lane map: row = lane&31, k = 8*kgrp + elem; B symmetric. Any
// consistent sub-k permutation cancels between A and B; C/D map is the
// HW-verified (col=lane&31, row=(reg&3)+8*(reg>>2)+4*(lane>>5)).
// ---------------------------------------------------------------------------
__global__ __launch_bounds__(256, 4)
void k1_gemm1(const float* __restrict__ outs, const int* __restrict__ rels_pos,
              const ushort* __restrict__ w1hi, const ushort* __restrict__ w1lo,
              const float* __restrict__ b1, float* __restrict__ h)
{
    const int b  = blockIdx.z;
    const int n0 = blockIdx.x * 128;
    const int i0 = blockIdx.y * 64;
    const int num = rels_pos[2 * b + 1];
    if (i0 >= num) return;
    const int start = rels_pos[2 * b + 0];

    __shared__ __bf16 Ah[4][64][8];      // 4 KB
    __shared__ __bf16 Al[4][64][8];      // 4 KB
    __shared__ __bf16 Bh[4][128][8];     // 8 KB
    __shared__ __bf16 Bl[4][128][8];     // 8 KB

    const int tid = threadIdx.x;

    // --- A staging map: thread = (row 0..63, k-octet 0..3) ---
    const int srow = tid & 63;
    const int sg   = tid >> 6;
    const int irow = i0 + srow;                       // clamped reads, safe
    int p1 = start + 4 * irow;     p1 = min(max(p1, 0), SS - 1);
    int p2 = start + 4 * irow + 2; p2 = min(max(p2, 0), SS - 1);
    const float* arow1 = outs + (size_t)(b * SS + p1) * HH;
    const float* arow2 = outs + (size_t)(b * SS + p2) * HH;

    // --- B staging map: thread covers (col 0..127) x 2 k-octets ---
    const int bc  = tid & 127;
    const int bg1 = tid >> 7;                         // 0,1
    const int bg2 = 2 + (tid >> 7);                   // 2,3
    const bf16x8* WH = (const bf16x8*)w1hi;
    const bf16x8* WL = (const bf16x8*)w1lo;

    // --- wave map: 2x2 waves of 32x64 ---
    const int lane = tid & 63;
    const int wid  = tid >> 6;
    const int wr   = wid >> 1;
    const int wc   = wid & 1;
    const int l31  = lane & 31;
    const int lhi  = lane >> 5;

    f32x16 acc[2];
    #pragma unroll
    for (int n = 0; n < 2; ++n)
        #pragma unroll
        for (int j = 0; j < 16; ++j) acc[n][j] = 0.f;

    // register prefetch of k-tile 0
    float4 aU, aV;
    bf16x8 pB0, pB1, pB2, pB3;
    {
        const int k = sg * 8;
        const float* s = arow1 + k;                   // k<768 at kt=0
        aU = *(const float4*)(s);
        aV = *(const float4*)(s + 4);
        const size_t i1 = (size_t)bg1 * 768 + n0 + bc;
        const size_t i2 = (size_t)bg2 * 768 + n0 + bc;
        pB0 = WH[i1]; pB1 = WL[i1]; pB2 = WH[i2]; pB3 = WL[i2];
    }

    for (int kt = 0; kt < KTOT / 32; ++kt) {
        // convert A chunk and store staged tile to LDS
        {
            const float fa[8] = {aU.x, aU.y, aU.z, aU.w, aV.x, aV.y, aV.z, aV.w};
            bf16x8 ah, al;
            #pragma unroll
            for (int j = 0; j < 8; ++j) {
                const __bf16 hb = (__bf16)fa[j];
                ah[j] = hb;
                al[j] = (__bf16)(fa[j] - (float)hb);
            }
            *(bf16x8*)&Ah[sg][srow][0] = ah;
            *(bf16x8*)&Al[sg][srow][0] = al;
            *(bf16x8*)&Bh[bg1][bc][0]  = pB0;
            *(bf16x8*)&Bl[bg1][bc][0]  = pB1;
            *(bf16x8*)&Bh[bg2][bc][0]  = pB2;
            *(bf16x8*)&Bl[bg2][bc][0]  = pB3;
        }
        __syncthreads();

        // issue next k-tile's global loads (covered by the MFMA block below)
        if (kt + 1 < KTOT / 32) {
            const int k0 = (kt + 1) * 32;
            const int k  = k0 + sg * 8;               // octet never straddles HH
            const float* s = (k < HH) ? (arow1 + k) : (arow2 + (k - HH));
            aU = *(const float4*)(s);
            aV = *(const float4*)(s + 4);
            const size_t base = (size_t)(k0 >> 3) * 768 + n0 + bc;
            const size_t i1 = base + (size_t)bg1 * 768;
            const size_t i2 = base + (size_t)bg2 * 768;
            pB0 = WH[i1]; pB1 = WL[i1]; pB2 = WH[i2]; pB3 = WL[i2];
        }

        // MFMA: 2 sub-steps (K=16 each) x 2 n-tiles x 3 passes
        #pragma unroll
        for (int s = 0; s < 2; ++s) {
            const int kg   = 2 * s + lhi;
            const int arow = wr * 32 + l31;
            const bf16x8 xh = *(const bf16x8*)&Ah[kg][arow][0];
            const bf16x8 xl = *(const bf16x8*)&Al[kg][arow][0];
            #pragma unroll
            for (int n = 0; n < 2; ++n) {
                const int bcol = wc * 64 + n * 32 + l31;
                const bf16x8 yh = *(const bf16x8*)&Bh[kg][bcol][0];
                const bf16x8 yl = *(const bf16x8*)&Bl[kg][bcol][0];
                acc[n] = __builtin_amdgcn_mfma_f32_32x32x16_bf16(xh, yh, acc[n], 0, 0, 0);
                acc[n] = __builtin_amdgcn_mfma_f32_32x32x16_bf16(xh, yl, acc[n], 0, 0, 0);
                acc[n] = __builtin_amdgcn_mfma_f32_32x32x16_bf16(xl, yh, acc[n], 0, 0, 0);
            }
        }
        __syncthreads();
    }

    // epilogue: bias + relu + store (C/D map verified: col=lane&31,
    // row=(reg&3)+8*(reg>>2)+4*(lane>>5))
    #pragma unroll
    for (int n = 0; n < 2; ++n) {
        const int colg = n0 + wc * 64 + n * 32 + l31;
        const float bv = b1[colg];
        #pragma unroll
        for (int j = 0; j < 16; ++j) {
            const int row = (j & 3) + 8 * (j >> 2) + 4 * lhi;
            const int i = i0 + wr * 32 + row;
            if (i < MAXN)
                h[((size_t)b * MAXN + i) * MIDD + colg] = fmaxf(acc[n][j] + bv, 0.f);
        }
    }
}

// ---------------------------------------------------------------------------
// K2: fused GEMM2 + bias + log-softmax + NLL + argmax (unchanged from r5).
// Block = 16 rows, 4 waves x 4 rows. Lane l owns cols l and l+64.
// h tile staged ONCE to LDS transposed [k][row]; W2 via register dbuf.
// ---------------------------------------------------------------------------
__global__ __launch_bounds__(256, 2)
void k2_head(const float* __restrict__ h, const int* __restrict__ rels,
             const int* __restrict__ rels_pos,
             const float* __restrict__ W2, const float* __restrict__ b2,
             float* __restrict__ out, float* __restrict__ partials)
{
    const int b   = blockIdx.y;
    const int i0  = blockIdx.x * 16;
    const int num = rels_pos[2 * b + 1];
    const int tid = threadIdx.x;
    const int blk = blockIdx.y * gridDim.x + blockIdx.x;

    if (tid < 16) {                              // masked rows: pred = label = -1
        const int i = i0 + tid;
        if (i < MAXN && i >= num) {
            out[1 + b * MAXN + i] = -1.0f;
            out[1 + BB * MAXN + b * MAXN + i] = -1.0f;
        }
    }
    if (i0 >= num) { if (tid == 0) partials[blk] = 0.f; return; }

    __shared__ __align__(16) float hs[MIDD][16]; // [k][row], 49 KB
    __shared__ float wave_nll[4];

    {
        const int row = tid & 15;
        const int kc0 = (tid >> 4) * 4;
        const int hrow_i = min(i0 + row, MAXN - 1);
        const float* hrow = h + ((size_t)b * MAXN + hrow_i) * MIDD;
        #pragma unroll
        for (int j = 0; j < 12; ++j) {
            const int k = kc0 + j * 64;
            const float4 v = *(const float4*)(hrow + k);
            hs[k + 0][row] = v.x;
            hs[k + 1][row] = v.y;
            hs[k + 2][row] = v.z;
            hs[k + 3][row] = v.w;
        }
    }
    __syncthreads();

    const int lane = tid & 63;
    const int wv   = tid >> 6;
    const int c    = lane;
    const bool has2 = (lane + 64) < LBL;
    const int c2   = has2 ? (lane + 64) : (LBL - 1);

    float acc0[4], acc1[4];
    #pragma unroll
    for (int r = 0; r < 4; ++r) { acc0[r] = 0.f; acc1[r] = 0.f; }

    float wA[8], wB[8], nAr[8], nBr[8];
    #pragma unroll
    for (int j = 0; j < 8; ++j) {
        wA[j] = W2[(size_t)j * LBL + c];
        wB[j] = W2[(size_t)j * LBL + c2];
    }
    for (int kbase = 0; kbase < MIDD; kbase += 8) {
        const bool more = (kbase + 8) < MIDD;
        if (more) {
            #pragma unroll
            for (int j = 0; j < 8; ++j) {
                nAr[j] = W2[(size_t)(kbase + 8 + j) * LBL + c];
                nBr[j] = W2[(size_t)(kbase + 8 + j) * LBL + c2];
            }
        }
        #pragma unroll
        for (int j = 0; j < 8; ++j) {
            const float4 hv = *(const float4*)&hs[kbase + j][wv * 4];
            acc0[0] += hv.x * wA[j]; acc0[1] += hv.y * wA[j];
            acc0[2] += hv.z * wA[j]; acc0[3] += hv.w * wA[j];
            acc1[0] += hv.x * wB[j]; acc1[1] += hv.y * wB[j];
            acc1[2] += hv.z * wB[j]; acc1[3] += hv.w * wB[j];
        }
        if (more) {
            #pragma unroll
            for (int j = 0; j < 8; ++j) { wA[j] = nAr[j]; wB[j] = nBr[j]; }
        }
    }
    const float bc  = b2[c];
    const float bc2 = b2[c2];
    #pragma unroll
    for (int r = 0; r < 4; ++r) { acc0[r] += bc; acc1[r] += bc2; }

    float nll_acc = 0.f;
    #pragma unroll
    for (int r = 0; r < 4; ++r) {
        const int i = i0 + wv * 4 + r;
        if (i >= num || i >= MAXN) continue;
        const float v1 = acc0[r];
        const float v2 = has2 ? acc1[r] : -INFINITY;
        float bv = v1; int bi = c;
        if (v2 > v1) { bv = v2; bi = lane + 64; }
        #pragma unroll
        for (int off = 32; off > 0; off >>= 1) {
            const float ov = __shfl_xor(bv, off);
            const int   oi = __shfl_xor(bi, off);
            if (ov > bv || (ov == bv && oi < bi)) { bv = ov; bi = oi; }
        }
        float se = expf(v1 - bv) + (has2 ? expf(v2 - bv) : 0.f);
        #pragma unroll
        for (int off = 32; off > 0; off >>= 1) se += __shfl_xor(se, off);
        const int lbl = rels[b * MAXN + i];
        float tv = (c == lbl ? v1 : 0.f) + ((has2 && (lane + 64) == lbl) ? v2 : 0.f);
        #pragma unroll
        for (int off = 32; off > 0; off >>= 1) tv += __shfl_xor(tv, off);
        const float nll = bv + logf(se) - tv;
        if (lane == 0) {
            nll_acc += nll;
            out[1 + b * MAXN + i] = (float)bi;
            out[1 + BB * MAXN + b * MAXN + i] = (float)lbl;
        }
    }
    if (lane == 0) wave_nll[wv] = nll_acc;
    __syncthreads();
    if (tid == 0)
        partials[blk] = wave_nll[0] + wave_nll[1] + wave_nll[2] + wave_nll[3];
}

// ---------------------------------------------------------------------------
// K3: reduce partial NLL sums, divide by mask count, write loss.
// ---------------------------------------------------------------------------
__global__ void k3_final(const float* __restrict__ partials,
                         const int* __restrict__ rels_pos, float* __restrict__ out)
{
    const int lane = threadIdx.x;   // 64 threads
    float v = 0.f;
    for (int idx = lane; idx < K2_XTILES * BB; idx += 64) v += partials[idx];
    #pragma unroll
    for (int off = 32; off > 0; off >>= 1) v += __shfl_xor(v, off);
    float cnt = (lane < BB) ? (float)min(max(rels_pos[2 * lane + 1], 0), MAXN) : 0.f;
    #pragma unroll
    for (int off = 32; off > 0; off >>= 1) cnt += __shfl_xor(cnt, off);
    if (lane == 0) out[0] = v / cnt;
}

extern "C" void kernel_launch(void* const* d_in, const int* in_sizes, int n_in,
                              void* d_out, int out_size, void* d_ws, size_t ws_size,
                              hipStream_t stream)
{
    const float* outs     = (const float*)d_in[0];
    const int*   rels     = (const int*)  d_in[1];
    const int*   rels_pos = (const int*)  d_in[2];
    const float* W1       = (const float*)d_in[3];
    const float* b1       = (const float*)d_in[4];
    const float* W2       = (const float*)d_in[5];
    const float* b2       = (const float*)d_in[6];
    float* out = (float*)d_out;

    float*  h        = (float*)d_ws;                       // 6400 x 768 f32 (19.7 MB)
    float*  partials = h + (size_t)BB * MAXN * MIDD;       // 400 floats
    ushort* w1hi     = (ushort*)(partials + K2_XTILES * BB);
    ushort* w1lo     = w1hi + (size_t)W1S_JOBS * 8;        // +2.36 MB each

    hipLaunchKernelGGL(k0_split, dim3((W1S_JOBS + 255) / 256), dim3(256), 0, stream,
                       W1, w1hi, w1lo);

    dim3 g1(MIDD / 128, (MAXN + 63) / 64, BB);             // (6, 7, 16)
    hipLaunchKernelGGL(k1_gemm1, g1, dim3(256), 0, stream,
                       outs, rels_pos, w1hi, w1lo, b1, h);

    dim3 g2(K2_XTILES, BB);                                // (25, 16)
    hipLaunchKernelGGL(k2_head, g2, dim3(256), 0, stream,
                       h, rels, rels_pos, W2, b2, out, partials);

    hipLaunchKernelGGL(k3_final, dim3(1), dim3(64), 0, stream, partials, rels_pos, out);
}

// Round 7
// 287.317 us; speedup vs baseline: 1.3391x; 1.0387x over previous
//
#include <hip/hip_runtime.h>
#include <hip/hip_bf16.h>
#include <math.h>

#define BB   16
#define SS   2048
#define HH   768
#define MAXN 400
#define LBL  97
#define MIDD 768
#define KTOT 1536   // 2*HH

#define K2_XTILES 25                      // ceil(400/16)
#define W1S_JOBS  (192 * 768)             // [k/8][col] b128 units per plane
#define K1_RT     7                       // ceil(400/64)
#define K1_GROUPS (K1_RT * BB)            // 112
#define K1_BLOCKS (K1_GROUPS * 6)         // 672

typedef __attribute__((ext_vector_type(8)))  __bf16 bf16x8;
typedef __attribute__((ext_vector_type(16))) float  f32x16;

// ---------------------------------------------------------------------------
// K0: split W1 (f32 [1536][768]) into hi/lo bf16 planes, layout [k>>3][col][8]
// so K1 can load B-fragments as coalesced b128 and store b128 to LDS.
// ---------------------------------------------------------------------------
__global__ __launch_bounds__(256)
void k0_split(const float* __restrict__ W1, ushort* __restrict__ hi,
              ushort* __restrict__ lo)
{
    const int job = blockIdx.x * 256 + threadIdx.x;   // 0..147455
    if (job >= W1S_JOBS) return;
    const int g   = job / 768;                        // k-octet 0..191
    const int col = job - g * 768;
    bf16x8 hv, lv;
    #pragma unroll
    for (int j = 0; j < 8; ++j) {
        const float f = W1[(size_t)(g * 8 + j) * MIDD + col];
        const __bf16 hb = (__bf16)f;                  // RNE
        hv[j] = hb;
        lv[j] = (__bf16)(f - (float)hb);
    }
    ((bf16x8*)hi)[job] = hv;
    ((bf16x8*)lo)[job] = lv;
}

// ---------------------------------------------------------------------------
// K1: fused gather + GEMM1 + bias + relu via bf16 3-pass split MFMA.
// tile BM=64 x BN=128 x BK=32; 4 waves (2r x 2c), each 32x64.
// NEW vs r6:
//  * 2-deep global prefetch: loads for k-tile kt+2 issued while kt computes,
//    so the vmcnt wait at the LDS-write has ~2 full iterations of cover.
//  * XCD swizzle: all 6 n-tiles of one (rt,b) group land on one XCD
//    (xcd = gid&7 round-robin assumption) -> A-rows hit that L2 once.
// ---------------------------------------------------------------------------
__global__ __launch_bounds__(256, 2)
void k1_gemm1(const float* __restrict__ outs, const int* __restrict__ rels_pos,
              const ushort* __restrict__ w1hi, const ushort* __restrict__ w1lo,
              const float* __restrict__ b1, float* __restrict__ h)
{
    // --- swizzled tile decode: group g=(rt,b) gets its 6 n-tiles on one XCD
    const int gid = blockIdx.x;
    const int idx = gid >> 3;
    const int g   = (gid & 7) + 8 * (idx / 6);        // 0..111
    const int m   = idx % 6;                          // n-tile
    const int rt  = g % K1_RT;
    const int b   = g / K1_RT;
    const int n0  = m * 128;
    const int i0  = rt * 64;

    const int num = rels_pos[2 * b + 1];
    if (i0 >= num) return;
    const int start = rels_pos[2 * b + 0];

    __shared__ __bf16 Ah[4][64][8];      // 4 KB
    __shared__ __bf16 Al[4][64][8];      // 4 KB
    __shared__ __bf16 Bh[4][128][8];     // 8 KB
    __shared__ __bf16 Bl[4][128][8];     // 8 KB

    const int tid = threadIdx.x;

    // --- A staging map: thread = (row 0..63, k-octet 0..3) ---
    const int srow = tid & 63;
    const int sg   = tid >> 6;
    const int irow = i0 + srow;                       // clamped reads, safe
    int p1 = start + 4 * irow;     p1 = min(max(p1, 0), SS - 1);
    int p2 = start + 4 * irow + 2; p2 = min(max(p2, 0), SS - 1);
    const float* arow1 = outs + (size_t)(b * SS + p1) * HH;
    const float* arow2 = outs + (size_t)(b * SS + p2) * HH;

    // --- B staging map: thread covers (col 0..127) x 2 k-octets ---
    const int bc  = tid & 127;
    const int bg1 = tid >> 7;                         // 0,1
    const int bg2 = 2 + (tid >> 7);                   // 2,3
    const bf16x8* WH = (const bf16x8*)w1hi;
    const bf16x8* WL = (const bf16x8*)w1lo;

    // --- wave map: 2x2 waves of 32x64 ---
    const int lane = tid & 63;
    const int wid  = tid >> 6;
    const int wr   = wid >> 1;
    const int wc   = wid & 1;
    const int l31  = lane & 31;
    const int lhi  = lane >> 5;

    f32x16 acc[2];
    #pragma unroll
    for (int n = 0; n < 2; ++n)
        #pragma unroll
        for (int j = 0; j < 16; ++j) acc[n][j] = 0.f;

    // ---- 2-deep prefetch register sets (named, no dynamic indexing) ----
    float4 aU0, aV0, aU1, aV1;
    bf16x8 pB00, pB01, pB02, pB03, pB10, pB11, pB12, pB13;

    // load set0 <- k-tile 0, set1 <- k-tile 1
    {
        const int k = sg * 8;
        const float* s = arow1 + k;                   // kt=0: k<768
        aU0 = *(const float4*)(s);
        aV0 = *(const float4*)(s + 4);
        const size_t i1 = (size_t)bg1 * 768 + n0 + bc;
        const size_t i2 = (size_t)bg2 * 768 + n0 + bc;
        pB00 = WH[i1]; pB01 = WL[i1]; pB02 = WH[i2]; pB03 = WL[i2];
    }
    {
        const int k = 32 + sg * 8;                    // kt=1: k<768
        const float* s = arow1 + k;
        aU1 = *(const float4*)(s);
        aV1 = *(const float4*)(s + 4);
        const size_t base = (size_t)(32 >> 3) * 768 + n0 + bc;
        const size_t i1 = base + (size_t)bg1 * 768;
        const size_t i2 = base + (size_t)bg2 * 768;
        pB10 = WH[i1]; pB11 = WL[i1]; pB12 = WH[i2]; pB13 = WL[i2];
    }

    #define K1_STAGE(AU, AV, P0, P1_, P2_, P3_)                               \
        {                                                                     \
            const float fa[8] = {AU.x, AU.y, AU.z, AU.w,                      \
                                 AV.x, AV.y, AV.z, AV.w};                     \
            bf16x8 ah, al;                                                    \
            _Pragma("unroll")                                                 \
            for (int j = 0; j < 8; ++j) {                                     \
                const __bf16 hb = (__bf16)fa[j];                              \
                ah[j] = hb;                                                   \
                al[j] = (__bf16)(fa[j] - (float)hb);                          \
            }                                                                 \
            *(bf16x8*)&Ah[sg][srow][0] = ah;                                  \
            *(bf16x8*)&Al[sg][srow][0] = al;                                  \
            *(bf16x8*)&Bh[bg1][bc][0]  = P0;                                  \
            *(bf16x8*)&Bl[bg1][bc][0]  = P1_;                                 \
            *(bf16x8*)&Bh[bg2][bc][0]  = P2_;                                 \
            *(bf16x8*)&Bl[bg2][bc][0]  = P3_;                                 \
        }

    #define K1_LOAD(AU, AV, P0, P1_, P2_, P3_, KT)                            \
        {                                                                     \
            const int k0 = (KT) * 32;                                         \
            const int k  = k0 + sg * 8;                                       \
            const float* s = (k < HH) ? (arow1 + k) : (arow2 + (k - HH));     \
            AU = *(const float4*)(s);                                         \
            AV = *(const float4*)(s + 4);                                     \
            const size_t base = (size_t)(k0 >> 3) * 768 + n0 + bc;            \
            const size_t i1 = base + (size_t)bg1 * 768;                       \
            const size_t i2 = base + (size_t)bg2 * 768;                       \
            P0 = WH[i1]; P1_ = WL[i1]; P2_ = WH[i2]; P3_ = WL[i2];            \
        }

    #define K1_MFMA()                                                         \
        _Pragma("unroll")                                                     \
        for (int s = 0; s < 2; ++s) {                                         \
            const int kg   = 2 * s + lhi;                                     \
            const int arow = wr * 32 + l31;                                   \
            const bf16x8 xh = *(const bf16x8*)&Ah[kg][arow][0];               \
            const bf16x8 xl = *(const bf16x8*)&Al[kg][arow][0];               \
            _Pragma("unroll")                                                 \
            for (int n = 0; n < 2; ++n) {                                     \
                const int bcol = wc * 64 + n * 32 + l31;                      \
                const bf16x8 yh = *(const bf16x8*)&Bh[kg][bcol][0];           \
                const bf16x8 yl = *(const bf16x8*)&Bl[kg][bcol][0];           \
                acc[n] = __builtin_amdgcn_mfma_f32_32x32x16_bf16(xh, yh, acc[n], 0, 0, 0); \
                acc[n] = __builtin_amdgcn_mfma_f32_32x32x16_bf16(xh, yl, acc[n], 0, 0, 0); \
                acc[n] = __builtin_amdgcn_mfma_f32_32x32x16_bf16(xl, yh, acc[n], 0, 0, 0); \
            }                                                                 \
        }

    for (int kt = 0; kt < KTOT / 32; kt += 2) {
        // ---- even iter: consume set0 ----
        K1_STAGE(aU0, aV0, pB00, pB01, pB02, pB03);
        __syncthreads();
        if (kt + 2 < KTOT / 32) K1_LOAD(aU0, aV0, pB00, pB01, pB02, pB03, kt + 2);
        K1_MFMA();
        __syncthreads();
        // ---- odd iter: consume set1 ----
        K1_STAGE(aU1, aV1, pB10, pB11, pB12, pB13);
        __syncthreads();
        if (kt + 3 < KTOT / 32) K1_LOAD(aU1, aV1, pB10, pB11, pB12, pB13, kt + 3);
        K1_MFMA();
        __syncthreads();
    }
    #undef K1_STAGE
    #undef K1_LOAD
    #undef K1_MFMA

    // epilogue: bias + relu + store (C/D map verified: col=lane&31,
    // row=(reg&3)+8*(reg>>2)+4*(lane>>5))
    #pragma unroll
    for (int n = 0; n < 2; ++n) {
        const int colg = n0 + wc * 64 + n * 32 + l31;
        const float bv = b1[colg];
        #pragma unroll
        for (int j = 0; j < 16; ++j) {
            const int row = (j & 3) + 8 * (j >> 2) + 4 * lhi;
            const int i = i0 + wr * 32 + row;
            if (i < MAXN)
                h[((size_t)b * MAXN + i) * MIDD + colg] = fmaxf(acc[n][j] + bv, 0.f);
        }
    }
}

// ---------------------------------------------------------------------------
// K2: fused GEMM2 + bias + log-softmax + NLL + argmax (unchanged).
// ---------------------------------------------------------------------------
__global__ __launch_bounds__(256, 2)
void k2_head(const float* __restrict__ h, const int* __restrict__ rels,
             const int* __restrict__ rels_pos,
             const float* __restrict__ W2, const float* __restrict__ b2,
             float* __restrict__ out, float* __restrict__ partials)
{
    const int b   = blockIdx.y;
    const int i0  = blockIdx.x * 16;
    const int num = rels_pos[2 * b + 1];
    const int tid = threadIdx.x;
    const int blk = blockIdx.y * gridDim.x + blockIdx.x;

    if (tid < 16) {                              // masked rows: pred = label = -1
        const int i = i0 + tid;
        if (i < MAXN && i >= num) {
            out[1 + b * MAXN + i] = -1.0f;
            out[1 + BB * MAXN + b * MAXN + i] = -1.0f;
        }
    }
    if (i0 >= num) { if (tid == 0) partials[blk] = 0.f; return; }

    __shared__ __align__(16) float hs[MIDD][16]; // [k][row], 49 KB
    __shared__ float wave_nll[4];

    {
        const int row = tid & 15;
        const int kc0 = (tid >> 4) * 4;
        const int hrow_i = min(i0 + row, MAXN - 1);
        const float* hrow = h + ((size_t)b * MAXN + hrow_i) * MIDD;
        #pragma unroll
        for (int j = 0; j < 12; ++j) {
            const int k = kc0 + j * 64;
            const float4 v = *(const float4*)(hrow + k);
            hs[k + 0][row] = v.x;
            hs[k + 1][row] = v.y;
            hs[k + 2][row] = v.z;
            hs[k + 3][row] = v.w;
        }
    }
    __syncthreads();

    const int lane = tid & 63;
    const int wv   = tid >> 6;
    const int c    = lane;
    const bool has2 = (lane + 64) < LBL;
    const int c2   = has2 ? (lane + 64) : (LBL - 1);

    float acc0[4], acc1[4];
    #pragma unroll
    for (int r = 0; r < 4; ++r) { acc0[r] = 0.f; acc1[r] = 0.f; }

    float wA[8], wB[8], nAr[8], nBr[8];
    #pragma unroll
    for (int j = 0; j < 8; ++j) {
        wA[j] = W2[(size_t)j * LBL + c];
        wB[j] = W2[(size_t)j * LBL + c2];
    }
    for (int kbase = 0; kbase < MIDD; kbase += 8) {
        const bool more = (kbase + 8) < MIDD;
        if (more) {
            #pragma unroll
            for (int j = 0; j < 8; ++j) {
                nAr[j] = W2[(size_t)(kbase + 8 + j) * LBL + c];
                nBr[j] = W2[(size_t)(kbase + 8 + j) * LBL + c2];
            }
        }
        #pragma unroll
        for (int j = 0; j < 8; ++j) {
            const float4 hv = *(const float4*)&hs[kbase + j][wv * 4];
            acc0[0] += hv.x * wA[j]; acc0[1] += hv.y * wA[j];
            acc0[2] += hv.z * wA[j]; acc0[3] += hv.w * wA[j];
            acc1[0] += hv.x * wB[j]; acc1[1] += hv.y * wB[j];
            acc1[2] += hv.z * wB[j]; acc1[3] += hv.w * wB[j];
        }
        if (more) {
            #pragma unroll
            for (int j = 0; j < 8; ++j) { wA[j] = nAr[j]; wB[j] = nBr[j]; }
        }
    }
    const float bc  = b2[c];
    const float bc2 = b2[c2];
    #pragma unroll
    for (int r = 0; r < 4; ++r) { acc0[r] += bc; acc1[r] += bc2; }

    float nll_acc = 0.f;
    #pragma unroll
    for (int r = 0; r < 4; ++r) {
        const int i = i0 + wv * 4 + r;
        if (i >= num || i >= MAXN) continue;
        const float v1 = acc0[r];
        const float v2 = has2 ? acc1[r] : -INFINITY;
        float bv = v1; int bi = c;
        if (v2 > v1) { bv = v2; bi = lane + 64; }
        #pragma unroll
        for (int off = 32; off > 0; off >>= 1) {
            const float ov = __shfl_xor(bv, off);
            const int   oi = __shfl_xor(bi, off);
            if (ov > bv || (ov == bv && oi < bi)) { bv = ov; bi = oi; }
        }
        float se = expf(v1 - bv) + (has2 ? expf(v2 - bv) : 0.f);
        #pragma unroll
        for (int off = 32; off > 0; off >>= 1) se += __shfl_xor(se, off);
        const int lbl = rels[b * MAXN + i];
        float tv = (c == lbl ? v1 : 0.f) + ((has2 && (lane + 64) == lbl) ? v2 : 0.f);
        #pragma unroll
        for (int off = 32; off > 0; off >>= 1) tv += __shfl_xor(tv, off);
        const float nll = bv + logf(se) - tv;
        if (lane == 0) {
            nll_acc += nll;
            out[1 + b * MAXN + i] = (float)bi;
            out[1 + BB * MAXN + b * MAXN + i] = (float)lbl;
        }
    }
    if (lane == 0) wave_nll[wv] = nll_acc;
    __syncthreads();
    if (tid == 0)
        partials[blk] = wave_nll[0] + wave_nll[1] + wave_nll[2] + wave_nll[3];
}

// ---------------------------------------------------------------------------
// K3: reduce partial NLL sums, divide by mask count, write loss.
// ---------------------------------------------------------------------------
__global__ void k3_final(const float* __restrict__ partials,
                         const int* __restrict__ rels_pos, float* __restrict__ out)
{
    const int lane = threadIdx.x;   // 64 threads
    float v = 0.f;
    for (int idx = lane; idx < K2_XTILES * BB; idx += 64) v += partials[idx];
    #pragma unroll
    for (int off = 32; off > 0; off >>= 1) v += __shfl_xor(v, off);
    float cnt = (lane < BB) ? (float)min(max(rels_pos[2 * lane + 1], 0), MAXN) : 0.f;
    #pragma unroll
    for (int off = 32; off > 0; off >>= 1) cnt += __shfl_xor(cnt, off);
    if (lane == 0) out[0] = v / cnt;
}

extern "C" void kernel_launch(void* const* d_in, const int* in_sizes, int n_in,
                              void* d_out, int out_size, void* d_ws, size_t ws_size,
                              hipStream_t stream)
{
    const float* outs     = (const float*)d_in[0];
    const int*   rels     = (const int*)  d_in[1];
    const int*   rels_pos = (const int*)  d_in[2];
    const float* W1       = (const float*)d_in[3];
    const float* b1       = (const float*)d_in[4];
    const float* W2       = (const float*)d_in[5];
    const float* b2       = (const float*)d_in[6];
    float* out = (float*)d_out;

    float*  h        = (float*)d_ws;                       // 6400 x 768 f32 (19.7 MB)
    float*  partials = h + (size_t)BB * MAXN * MIDD;       // 400 floats
    ushort* w1hi     = (ushort*)(partials + K2_XTILES * BB);
    ushort* w1lo     = w1hi + (size_t)W1S_JOBS * 8;        // +2.36 MB each

    hipLaunchKernelGGL(k0_split, dim3((W1S_JOBS + 255) / 256), dim3(256), 0, stream,
                       W1, w1hi, w1lo);

    hipLaunchKernelGGL(k1_gemm1, dim3(K1_BLOCKS), dim3(256), 0, stream,
                       outs, rels_pos, w1hi, w1lo, b1, h);

    dim3 g2(K2_XTILES, BB);                                // (25, 16)
    hipLaunchKernelGGL(k2_head, g2, dim3(256), 0, stream,
                       h, rels, rels_pos, W2, b2, out, partials);

    hipLaunchKernelGGL(k3_final, dim3(1), dim3(64), 0, stream, partials, rels_pos, out);
}

// Round 8
// 273.487 us; speedup vs baseline: 1.4068x; 1.0506x over previous
//
#include <hip/hip_runtime.h>
#include <hip/hip_bf16.h>
#include <math.h>

#define BB   16
#define SS   2048
#define HH   768
#define MAXN 400
#define LBL  97
#define MIDD 768
#define KTOT 1536   // 2*HH

#define K2_XTILES 25                      // ceil(400/16)
#define W1S_JOBS  (192 * 768)             // [k/8][col] b128 units per plane
#define K1_RT     7                       // ceil(400/64)
#define K1_GROUPS (K1_RT * BB)            // 112
#define K1_SPLIT  4                       // split-K ways (K chunk = 384)
#define K1_UNITS  (K1_GROUPS * K1_SPLIT)  // 448
#define K1_BLOCKS (K1_UNITS * 6)          // 2688
#define K1_KI     (KTOT / 32 / K1_SPLIT)  // 12 k-iters per block

typedef __attribute__((ext_vector_type(8)))  __bf16 bf16x8;
typedef __attribute__((ext_vector_type(16))) float  f32x16;

// ---------------------------------------------------------------------------
// K0: split W1 (f32 [1536][768]) into hi/lo bf16 planes, layout [k>>3][col][8].
// ---------------------------------------------------------------------------
__global__ __launch_bounds__(256)
void k0_split(const float* __restrict__ W1, ushort* __restrict__ hi,
              ushort* __restrict__ lo)
{
    const int job = blockIdx.x * 256 + threadIdx.x;   // 0..147455
    if (job >= W1S_JOBS) return;
    const int g   = job / 768;                        // k-octet 0..191
    const int col = job - g * 768;
    bf16x8 hv, lv;
    #pragma unroll
    for (int j = 0; j < 8; ++j) {
        const float f = W1[(size_t)(g * 8 + j) * MIDD + col];
        const __bf16 hb = (__bf16)f;                  // RNE
        hv[j] = hb;
        lv[j] = (__bf16)(f - (float)hb);
    }
    ((bf16x8*)hi)[job] = hv;
    ((bf16x8*)lo)[job] = lv;
}

// ---------------------------------------------------------------------------
// K1: fused gather + GEMM1 via bf16 3-pass split MFMA, 4-way split-K.
// Each block: BM=64 x BN=128 x K=384 partial, atomicAdd into zeroed h.
// Grid ~2700 active blocks (~5/CU) -> waves/SIMD ~5: latency finally hidden.
// XCD swizzle: the 6 n-tiles of one (group,split) unit share an XCD L2.
// Bias+relu moved to K2.
// ---------------------------------------------------------------------------
__global__ __launch_bounds__(256, 2)
void k1_gemm1(const float* __restrict__ outs, const int* __restrict__ rels_pos,
              const ushort* __restrict__ w1hi, const ushort* __restrict__ w1lo,
              float* __restrict__ h)
{
    // --- swizzled decode: unit u=(g,s) gets its 6 n-tiles on one XCD ---
    const int gid = blockIdx.x;
    const int idx = gid >> 3;
    const int u   = (gid & 7) + 8 * (idx / 6);        // 0..447
    const int m   = idx % 6;                          // n-tile
    const int g   = u >> 2;                           // 0..111 (rt,b group)
    const int s   = u & 3;                            // split-K index
    const int rt  = g % K1_RT;
    const int b   = g / K1_RT;
    const int n0  = m * 128;
    const int i0  = rt * 64;
    const int ks  = s * K1_KI;                        // first k-iter (abs)

    const int num = rels_pos[2 * b + 1];
    if (i0 >= num) return;
    const int start = rels_pos[2 * b + 0];

    __shared__ __bf16 Ah[4][64][8];      // 4 KB
    __shared__ __bf16 Al[4][64][8];      // 4 KB
    __shared__ __bf16 Bh[4][128][8];     // 8 KB
    __shared__ __bf16 Bl[4][128][8];     // 8 KB

    const int tid = threadIdx.x;

    // --- A staging map: thread = (row 0..63, k-octet 0..3) ---
    const int srow = tid & 63;
    const int sg   = tid >> 6;
    const int irow = i0 + srow;                       // clamped reads, safe
    int p1 = start + 4 * irow;     p1 = min(max(p1, 0), SS - 1);
    int p2 = start + 4 * irow + 2; p2 = min(max(p2, 0), SS - 1);
    const float* arow1 = outs + (size_t)(b * SS + p1) * HH;
    const float* arow2 = outs + (size_t)(b * SS + p2) * HH;

    // --- B staging map: thread covers (col 0..127) x 2 k-octets ---
    const int bc  = tid & 127;
    const int bg1 = tid >> 7;                         // 0,1
    const int bg2 = 2 + (tid >> 7);                   // 2,3
    const bf16x8* WH = (const bf16x8*)w1hi;
    const bf16x8* WL = (const bf16x8*)w1lo;

    // --- wave map: 2x2 waves of 32x64 ---
    const int lane = tid & 63;
    const int wid  = tid >> 6;
    const int wr   = wid >> 1;
    const int wc   = wid & 1;
    const int l31  = lane & 31;
    const int lhi  = lane >> 5;

    f32x16 acc[2];
    #pragma unroll
    for (int n = 0; n < 2; ++n)
        #pragma unroll
        for (int j = 0; j < 16; ++j) acc[n][j] = 0.f;

    // ---- 2-deep prefetch register sets (named, no dynamic indexing) ----
    float4 aU0, aV0, aU1, aV1;
    bf16x8 pB00, pB01, pB02, pB03, pB10, pB11, pB12, pB13;

    #define K1_LOAD(AU, AV, P0, P1_, P2_, P3_, KT)                            \
        {                                                                     \
            const int k0 = (KT) * 32;                                         \
            const int k  = k0 + sg * 8;                                       \
            const float* sp = (k < HH) ? (arow1 + k) : (arow2 + (k - HH));    \
            AU = *(const float4*)(sp);                                        \
            AV = *(const float4*)(sp + 4);                                    \
            const size_t base = (size_t)(k0 >> 3) * 768 + n0 + bc;            \
            const size_t i1 = base + (size_t)bg1 * 768;                       \
            const size_t i2 = base + (size_t)bg2 * 768;                       \
            P0 = WH[i1]; P1_ = WL[i1]; P2_ = WH[i2]; P3_ = WL[i2];            \
        }

    #define K1_STAGE(AU, AV, P0, P1_, P2_, P3_)                               \
        {                                                                     \
            const float fa[8] = {AU.x, AU.y, AU.z, AU.w,                      \
                                 AV.x, AV.y, AV.z, AV.w};                     \
            bf16x8 ah, al;                                                    \
            _Pragma("unroll")                                                 \
            for (int j = 0; j < 8; ++j) {                                     \
                const __bf16 hb = (__bf16)fa[j];                              \
                ah[j] = hb;                                                   \
                al[j] = (__bf16)(fa[j] - (float)hb);                          \
            }                                                                 \
            *(bf16x8*)&Ah[sg][srow][0] = ah;                                  \
            *(bf16x8*)&Al[sg][srow][0] = al;                                  \
            *(bf16x8*)&Bh[bg1][bc][0]  = P0;                                  \
            *(bf16x8*)&Bl[bg1][bc][0]  = P1_;                                 \
            *(bf16x8*)&Bh[bg2][bc][0]  = P2_;                                 \
            *(bf16x8*)&Bl[bg2][bc][0]  = P3_;                                 \
        }

    #define K1_MFMA()                                                         \
        _Pragma("unroll")                                                     \
        for (int ss = 0; ss < 2; ++ss) {                                      \
            const int kg   = 2 * ss + lhi;                                    \
            const int arow = wr * 32 + l31;                                   \
            const bf16x8 xh = *(const bf16x8*)&Ah[kg][arow][0];               \
            const bf16x8 xl = *(const bf16x8*)&Al[kg][arow][0];               \
            _Pragma("unroll")                                                 \
            for (int n = 0; n < 2; ++n) {                                     \
                const int bcol = wc * 64 + n * 32 + l31;                      \
                const bf16x8 yh = *(const bf16x8*)&Bh[kg][bcol][0];           \
                const bf16x8 yl = *(const bf16x8*)&Bl[kg][bcol][0];           \
                acc[n] = __builtin_amdgcn_mfma_f32_32x32x16_bf16(xh, yh, acc[n], 0, 0, 0); \
                acc[n] = __builtin_amdgcn_mfma_f32_32x32x16_bf16(xh, yl, acc[n], 0, 0, 0); \
                acc[n] = __builtin_amdgcn_mfma_f32_32x32x16_bf16(xl, yh, acc[n], 0, 0, 0); \
            }                                                                 \
        }

    // prime the 2-deep pipe
    K1_LOAD(aU0, aV0, pB00, pB01, pB02, pB03, ks);
    K1_LOAD(aU1, aV1, pB10, pB11, pB12, pB13, ks + 1);

    const int ke = ks + K1_KI;
    for (int kt = ks; kt < ke; kt += 2) {
        // ---- even iter: consume set0 ----
        K1_STAGE(aU0, aV0, pB00, pB01, pB02, pB03);
        __syncthreads();
        if (kt + 2 < ke) K1_LOAD(aU0, aV0, pB00, pB01, pB02, pB03, kt + 2);
        K1_MFMA();
        __syncthreads();
        // ---- odd iter: consume set1 ----
        K1_STAGE(aU1, aV1, pB10, pB11, pB12, pB13);
        __syncthreads();
        if (kt + 3 < ke) K1_LOAD(aU1, aV1, pB10, pB11, pB12, pB13, kt + 3);
        K1_MFMA();
        __syncthreads();
    }
    #undef K1_STAGE
    #undef K1_LOAD
    #undef K1_MFMA

    // epilogue: atomic accumulate partial (bias+relu applied in K2)
    #pragma unroll
    for (int n = 0; n < 2; ++n) {
        const int colg = n0 + wc * 64 + n * 32 + l31;
        #pragma unroll
        for (int j = 0; j < 16; ++j) {
            const int row = (j & 3) + 8 * (j >> 2) + 4 * lhi;
            const int i = i0 + wr * 32 + row;
            if (i < MAXN)
                atomicAdd(&h[((size_t)b * MAXN + i) * MIDD + colg], acc[n][j]);
        }
    }
}

// ---------------------------------------------------------------------------
// K2: fused bias+relu + GEMM2 + bias + log-softmax + NLL + argmax.
// h now holds pre-activation (no bias); staging applies relu(h + b1).
// ---------------------------------------------------------------------------
__global__ __launch_bounds__(256, 2)
void k2_head(const float* __restrict__ h, const float* __restrict__ b1,
             const int* __restrict__ rels, const int* __restrict__ rels_pos,
             const float* __restrict__ W2, const float* __restrict__ b2,
             float* __restrict__ out, float* __restrict__ partials)
{
    const int b   = blockIdx.y;
    const int i0  = blockIdx.x * 16;
    const int num = rels_pos[2 * b + 1];
    const int tid = threadIdx.x;
    const int blk = blockIdx.y * gridDim.x + blockIdx.x;

    if (tid < 16) {                              // masked rows: pred = label = -1
        const int i = i0 + tid;
        if (i < MAXN && i >= num) {
            out[1 + b * MAXN + i] = -1.0f;
            out[1 + BB * MAXN + b * MAXN + i] = -1.0f;
        }
    }
    if (i0 >= num) { if (tid == 0) partials[blk] = 0.f; return; }

    __shared__ __align__(16) float hs[MIDD][16]; // [k][row], 49 KB
    __shared__ float wave_nll[4];

    {
        const int row = tid & 15;
        const int kc0 = (tid >> 4) * 4;
        const int hrow_i = min(i0 + row, MAXN - 1);
        const float* hrow = h + ((size_t)b * MAXN + hrow_i) * MIDD;
        #pragma unroll
        for (int j = 0; j < 12; ++j) {
            const int k = kc0 + j * 64;
            const float4 v  = *(const float4*)(hrow + k);
            const float4 bb = *(const float4*)(b1 + k);
            hs[k + 0][row] = fmaxf(v.x + bb.x, 0.f);
            hs[k + 1][row] = fmaxf(v.y + bb.y, 0.f);
            hs[k + 2][row] = fmaxf(v.z + bb.z, 0.f);
            hs[k + 3][row] = fmaxf(v.w + bb.w, 0.f);
        }
    }
    __syncthreads();

    const int lane = tid & 63;
    const int wv   = tid >> 6;
    const int c    = lane;
    const bool has2 = (lane + 64) < LBL;
    const int c2   = has2 ? (lane + 64) : (LBL - 1);

    float acc0[4], acc1[4];
    #pragma unroll
    for (int r = 0; r < 4; ++r) { acc0[r] = 0.f; acc1[r] = 0.f; }

    float wA[8], wB[8], nAr[8], nBr[8];
    #pragma unroll
    for (int j = 0; j < 8; ++j) {
        wA[j] = W2[(size_t)j * LBL + c];
        wB[j] = W2[(size_t)j * LBL + c2];
    }
    for (int kbase = 0; kbase < MIDD; kbase += 8) {
        const bool more = (kbase + 8) < MIDD;
        if (more) {
            #pragma unroll
            for (int j = 0; j < 8; ++j) {
                nAr[j] = W2[(size_t)(kbase + 8 + j) * LBL + c];
                nBr[j] = W2[(size_t)(kbase + 8 + j) * LBL + c2];
            }
        }
        #pragma unroll
        for (int j = 0; j < 8; ++j) {
            const float4 hv = *(const float4*)&hs[kbase + j][wv * 4];
            acc0[0] += hv.x * wA[j]; acc0[1] += hv.y * wA[j];
            acc0[2] += hv.z * wA[j]; acc0[3] += hv.w * wA[j];
            acc1[0] += hv.x * wB[j]; acc1[1] += hv.y * wB[j];
            acc1[2] += hv.z * wB[j]; acc1[3] += hv.w * wB[j];
        }
        if (more) {
            #pragma unroll
            for (int j = 0; j < 8; ++j) { wA[j] = nAr[j]; wB[j] = nBr[j]; }
        }
    }
    const float bc  = b2[c];
    const float bc2 = b2[c2];
    #pragma unroll
    for (int r = 0; r < 4; ++r) { acc0[r] += bc; acc1[r] += bc2; }

    float nll_acc = 0.f;
    #pragma unroll
    for (int r = 0; r < 4; ++r) {
        const int i = i0 + wv * 4 + r;
        if (i >= num || i >= MAXN) continue;
        const float v1 = acc0[r];
        const float v2 = has2 ? acc1[r] : -INFINITY;
        float bv = v1; int bi = c;
        if (v2 > v1) { bv = v2; bi = lane + 64; }
        #pragma unroll
        for (int off = 32; off > 0; off >>= 1) {
            const float ov = __shfl_xor(bv, off);
            const int   oi = __shfl_xor(bi, off);
            if (ov > bv || (ov == bv && oi < bi)) { bv = ov; bi = oi; }
        }
        float se = expf(v1 - bv) + (has2 ? expf(v2 - bv) : 0.f);
        #pragma unroll
        for (int off = 32; off > 0; off >>= 1) se += __shfl_xor(se, off);
        const int lbl = rels[b * MAXN + i];
        float tv = (c == lbl ? v1 : 0.f) + ((has2 && (lane + 64) == lbl) ? v2 : 0.f);
        #pragma unroll
        for (int off = 32; off > 0; off >>= 1) tv += __shfl_xor(tv, off);
        const float nll = bv + logf(se) - tv;
        if (lane == 0) {
            nll_acc += nll;
            out[1 + b * MAXN + i] = (float)bi;
            out[1 + BB * MAXN + b * MAXN + i] = (float)lbl;
        }
    }
    if (lane == 0) wave_nll[wv] = nll_acc;
    __syncthreads();
    if (tid == 0)
        partials[blk] = wave_nll[0] + wave_nll[1] + wave_nll[2] + wave_nll[3];
}

// ---------------------------------------------------------------------------
// K3: reduce partial NLL sums, divide by mask count, write loss.
// ---------------------------------------------------------------------------
__global__ void k3_final(const float* __restrict__ partials,
                         const int* __restrict__ rels_pos, float* __restrict__ out)
{
    const int lane = threadIdx.x;   // 64 threads
    float v = 0.f;
    for (int idx = lane; idx < K2_XTILES * BB; idx += 64) v += partials[idx];
    #pragma unroll
    for (int off = 32; off > 0; off >>= 1) v += __shfl_xor(v, off);
    float cnt = (lane < BB) ? (float)min(max(rels_pos[2 * lane + 1], 0), MAXN) : 0.f;
    #pragma unroll
    for (int off = 32; off > 0; off >>= 1) cnt += __shfl_xor(cnt, off);
    if (lane == 0) out[0] = v / cnt;
}

extern "C" void kernel_launch(void* const* d_in, const int* in_sizes, int n_in,
                              void* d_out, int out_size, void* d_ws, size_t ws_size,
                              hipStream_t stream)
{
    const float* outs     = (const float*)d_in[0];
    const int*   rels     = (const int*)  d_in[1];
    const int*   rels_pos = (const int*)  d_in[2];
    const float* W1       = (const float*)d_in[3];
    const float* b1       = (const float*)d_in[4];
    const float* W2       = (const float*)d_in[5];
    const float* b2       = (const float*)d_in[6];
    float* out = (float*)d_out;

    float*  h        = (float*)d_ws;                       // 6400 x 768 f32 (19.7 MB)
    float*  partials = h + (size_t)BB * MAXN * MIDD;       // 400 floats
    ushort* w1hi     = (ushort*)(partials + K2_XTILES * BB);
    ushort* w1lo     = w1hi + (size_t)W1S_JOBS * 8;        // +2.36 MB each

    // zero h (split-K atomic accumulator target)
    hipMemsetAsync(h, 0, (size_t)BB * MAXN * MIDD * sizeof(float), stream);

    hipLaunchKernelGGL(k0_split, dim3((W1S_JOBS + 255) / 256), dim3(256), 0, stream,
                       W1, w1hi, w1lo);

    hipLaunchKernelGGL(k1_gemm1, dim3(K1_BLOCKS), dim3(256), 0, stream,
                       outs, rels_pos, w1hi, w1lo, h);

    dim3 g2(K2_XTILES, BB);                                // (25, 16)
    hipLaunchKernelGGL(k2_head, g2, dim3(256), 0, stream,
                       h, b1, rels, rels_pos, W2, b2, out, partials);

    hipLaunchKernelGGL(k3_final, dim3(1), dim3(64), 0, stream, partials, rels_pos, out);
}